// Round 11
// baseline (63.339 us; speedup 1.0000x reference)
//
#include <hip/hip_runtime.h>
#include <hip/hip_fp16.h>

#define NIMG 2
#define CCH 256
#define FH 128
#define FW 128
#define FHW (FH * FW)
#define OUTH 7
#define OUTW 7
#define NPIX 49
#define NSAMP (NPIX * 4)
#define KROIS 1024
#define SCALE 0.0625f
#define OPITCH 260   // halves; 520 B row pitch
#define MAXJ 192     // block slots per XCD-group; j-loop handles overflow correctly

typedef float f32x4 __attribute__((ext_vector_type(4)));

// ---------------- fused: NCHW->NHWC fp16 transpose (blocks 0..8191) + ROI group sort (block 8192) ----
// 8 groups = (image<<2)|rowquarter(center); 16 locality cells within each group.
// Output is bit-identical for any within-bucket order; only L2 locality depends on it.
__global__ __launch_bounds__(256) void prep_fused(const float* __restrict__ in,
                                                  __half* __restrict__ out,
                                                  const float* __restrict__ rois,
                                                  int* __restrict__ perm,
                                                  int* __restrict__ bases) {
    const int bid = blockIdx.x;
    const int t = threadIdx.x;
    if (bid < 8192) {
        __shared__ float tile[32][33];
        const int b   = bid >> 12;
        const int rem = bid & 4095;
        const int c0  = (rem >> 9) << 5;
        const int hw0 = (rem & 511) << 5;
        const int tx = t & 31;
        const int ty = t >> 5;
        const float* src = in  + (size_t)b * CCH * FHW;
        __half*      dst = out + (size_t)b * FHW * CCH;
#pragma unroll
        for (int i = 0; i < 32; i += 8)
            tile[ty + i][tx] = src[(size_t)(c0 + ty + i) * FHW + hw0 + tx];
        __syncthreads();
#pragma unroll
        for (int i = 0; i < 32; i += 8)
            dst[(size_t)(hw0 + ty + i) * CCH + c0 + tx] = __float2half(tile[tx][ty + i]);
    } else {
        __shared__ int hist[128];
        __shared__ int basep[128];
        __shared__ int keyv[KROIS];
        __shared__ int rankv[KROIS];
        if (t < 128) hist[t] = 0;
        __syncthreads();
#pragma unroll
        for (int i = 0; i < 4; ++i) {
            const int roi = t + (i << 8);
            const float* r = rois + roi * 5;
            const int b = (int)r[0];
            const float cx = (r[1] + r[3]) * 0.5f * SCALE;
            const float cy = (r[2] + r[4]) * 0.5f * SCALE;
            const int qcx = min(max((int)cx, 0), FW - 1);
            const int qcy = min(max((int)cy, 0), FH - 1);
            const int g = (b << 2) | (qcy >> 5);                        // image, row-quarter
            const int cell = (((qcy & 31) >> 4) << 3) | (qcx >> 4);     // 2x8 16px cells
            const int key = (g << 4) | cell;                            // 128 bins
            keyv[roi] = key;
            rankv[roi] = atomicAdd(&hist[key], 1);
        }
        __syncthreads();
        if (t < 64) {  // one-wave exclusive scan over 128 bins (2/lane)
            const int a = hist[2 * t], c = hist[2 * t + 1];
            int s = a + c;
#pragma unroll
            for (int d = 1; d < 64; d <<= 1) {
                const int n = __shfl_up(s, d);
                if (t >= d) s += n;
            }
            const int excl = s - (a + c);
            basep[2 * t]     = excl;
            basep[2 * t + 1] = excl + a;
        }
        __syncthreads();
        if (t < 8) bases[t] = basep[t << 4];  // group starts
        if (t == 0) bases[8] = KROIS;
#pragma unroll
        for (int i = 0; i < 4; ++i) {
            const int roi = t + (i << 8);
            perm[basep[keyv[roi]] + rankv[roi]] = roi;
        }
    }
}

// ---------------- main RoIAlign: 8-way XCD partition = (image, row-quarter), full 256 ch ----------------
// One block per ROI. Lane owns 4 channels (dwordx2): a wave's 64 lanes x 8 B = 512 B
// = ALL 256 channels of one position per load -> half the VMEM instructions of the
// plane-split version at identical bytes. Partition footprint 32x128x256x2B = 2.1 MB <= L2.
__global__ __launch_bounds__(256, 4) void roi_align_nhwc(const __half* __restrict__ nhwc,
                                                         const float* __restrict__ rois,
                                                         const int* __restrict__ perm,
                                                         const int* __restrict__ bases,
                                                         float* __restrict__ out) {
    __shared__ __half obuf[NPIX * OPITCH];                 // 25,480 B
    __shared__ __align__(16) int   soff[NSAMP][4];         // 3,136 B
    __shared__ __align__(16) float swgt[NSAMP][4];         // 3,136 B
    const int bid = blockIdx.x;
    const int g = bid & 7;
    const int base  = bases[g];
    const int count = bases[g + 1] - base;
    const int t = threadIdx.x;
    const int lane = t & 63;
    const int wave = t >> 6;
    const int pstart = wave ? (12 * wave + 1) : 0;          // 0,13,25,37
    const int pcnt   = wave ? 12 : 13;
    const int laneoff = lane << 3;                          // 4-ch (8 B) lane slot

    for (int j = bid >> 3; j < count; j += MAXJ) {
        const int k = perm[base + j];
        const float* r = rois + k * 5;
        const int b = __builtin_amdgcn_readfirstlane((int)r[0]);

        // phase 0: one thread per (pix,sample) computes offsets+weights (exact ref math)
        if (t < NSAMP) {
            const float x1 = __fsub_rn(__fmul_rn(r[1], SCALE), 0.5f);
            const float y1 = __fsub_rn(__fmul_rn(r[2], SCALE), 0.5f);
            const float x2 = __fsub_rn(__fmul_rn(r[3], SCALE), 0.5f);
            const float y2 = __fsub_rn(__fmul_rn(r[4], SCALE), 0.5f);
            const float bw = __fdiv_rn(__fsub_rn(x2, x1), (float)OUTW);
            const float bh = __fdiv_rn(__fsub_rn(y2, y1), (float)OUTH);
            const int pix = t >> 2, s = t & 3;
            const int ph = pix / 7, pw = pix - ph * 7;
            const int sy = s >> 1, sx = s & 1;
            const float fy = (float)ph + (sy ? 0.75f : 0.25f);
            const float fx = (float)pw + (sx ? 0.75f : 0.25f);
            const float y = __fadd_rn(y1, __fmul_rn(fy, bh));
            const float x = __fadd_rn(x1, __fmul_rn(fx, bw));
            int o00 = 0, o01 = 0, o10 = 0, o11 = 0;
            float w00 = 0.f, w01 = 0.f, w10 = 0.f, w11 = 0.f;
            if (y > -1.0f && y < (float)FH && x > -1.0f && x < (float)FW) {
                const float yc = fmaxf(y, 0.0f);
                const float xc = fmaxf(x, 0.0f);
                int y0 = (int)yc; if (y0 > FH - 1) y0 = FH - 1;
                int x0 = (int)xc; if (x0 > FW - 1) x0 = FW - 1;
                const int y1i = min(y0 + 1, FH - 1);
                const int x1i = min(x0 + 1, FW - 1);
                const float ly = fminf(yc - (float)y0, 1.0f);
                const float lx = fminf(xc - (float)x0, 1.0f);
                const float hy = 1.0f - ly, hx = 1.0f - lx;
                w00 = hy * hx; w01 = hy * lx; w10 = ly * hx; w11 = ly * lx;
                o00 = (y0  * FW + x0 ) << 9;  // *512 B (256 fp16 channels per position)
                o01 = (y0  * FW + x1i) << 9;
                o10 = (y1i * FW + x0 ) << 9;
                o11 = (y1i * FW + x1i) << 9;
            }
            soff[t][0] = o00; soff[t][1] = o01; soff[t][2] = o10; soff[t][3] = o11;
            swgt[t][0] = w00; swgt[t][1] = w01; swgt[t][2] = w10; swgt[t][3] = w11;
        }
        __syncthreads();

        // phase 1: batch 16 dwordx2 loads per pixel into regs, then the fma_mix batch
        const char* gbase = (const char*)(nhwc + ((size_t)b * FHW << 8));
#pragma unroll
        for (int i = 0; i < 13; ++i) {
            if (i < pcnt) {
                const int pix = pstart + i;
                uint2 rv[16];
#pragma unroll
                for (int s = 0; s < 4; ++s) {
                    const int4 o = *(const int4*)(&soff[(pix << 2) + s][0]);
                    rv[4 * s + 0] = *(const uint2*)(gbase + (unsigned)(o.x + laneoff));
                    rv[4 * s + 1] = *(const uint2*)(gbase + (unsigned)(o.y + laneoff));
                    rv[4 * s + 2] = *(const uint2*)(gbase + (unsigned)(o.z + laneoff));
                    rv[4 * s + 3] = *(const uint2*)(gbase + (unsigned)(o.w + laneoff));
                }
                float acc0 = 0.f, acc1 = 0.f, acc2 = 0.f, acc3 = 0.f;
#pragma unroll
                for (int s = 0; s < 4; ++s) {
                    const f32x4 w = *(const f32x4*)(&swgt[(pix << 2) + s][0]);
#pragma unroll
                    for (int c = 0; c < 4; ++c) {
                        const float wc = (c == 0) ? w.x : (c == 1) ? w.y : (c == 2) ? w.z : w.w;
                        const __half2 lo = *(const __half2*)&rv[4 * s + c].x;
                        const __half2 hi = *(const __half2*)&rv[4 * s + c].y;
                        acc0 = fmaf(wc, __half2float(lo.x), acc0);
                        acc1 = fmaf(wc, __half2float(lo.y), acc1);
                        acc2 = fmaf(wc, __half2float(hi.x), acc2);
                        acc3 = fmaf(wc, __half2float(hi.y), acc3);
                    }
                }
                const __half2 h01 = __floats2half2_rn(acc0 * 0.25f, acc1 * 0.25f);
                const __half2 h23 = __floats2half2_rn(acc2 * 0.25f, acc3 * 0.25f);
                uint2 packed;
                packed.x = *(const unsigned*)&h01;
                packed.y = *(const unsigned*)&h23;
                *(uint2*)&obuf[pix * OPITCH + (lane << 2)] = packed;
            }
        }
        __syncthreads();

        // phase 2: coalesced writeout out[k][c][pix] (12544 floats), non-temporal
        float* op = out + (size_t)k * (CCH * NPIX);
        for (int f4 = t; f4 < (CCH * NPIX) / 4; f4 += 256) {
            const int f = f4 << 2;
            f32x4 o;
            {
                const int fi = f + 0; const int c = fi / NPIX; const int pp = fi - c * NPIX;
                o.x = __half2float(obuf[pp * OPITCH + c]);
            }
            {
                const int fi = f + 1; const int c = fi / NPIX; const int pp = fi - c * NPIX;
                o.y = __half2float(obuf[pp * OPITCH + c]);
            }
            {
                const int fi = f + 2; const int c = fi / NPIX; const int pp = fi - c * NPIX;
                o.z = __half2float(obuf[pp * OPITCH + c]);
            }
            {
                const int fi = f + 3; const int c = fi / NPIX; const int pp = fi - c * NPIX;
                o.w = __half2float(obuf[pp * OPITCH + c]);
            }
            __builtin_nontemporal_store(o, (f32x4*)(op + f));
        }
        __syncthreads();  // protect obuf/soff/swgt before next j overwrites
    }
}

// ---------------- fallback: direct NCHW f32, one thread per output element ----------------
__global__ __launch_bounds__(256) void roi_align_naive(const float* __restrict__ feat,
                                                       const float* __restrict__ rois,
                                                       float* __restrict__ out) {
    const size_t idx = (size_t)blockIdx.x * 256 + threadIdx.x;
    const size_t total = (size_t)KROIS * CCH * NPIX;
    if (idx >= total) return;
    const int pix = (int)(idx % NPIX);
    const int t1  = (int)(idx / NPIX);
    const int c   = t1 % CCH;
    const int k   = t1 / CCH;
    const int ph = pix / 7;
    const int pw = pix - ph * 7;

    const float* r = rois + k * 5;
    const int b = (int)r[0];
    const float x1 = __fsub_rn(__fmul_rn(r[1], SCALE), 0.5f);
    const float y1 = __fsub_rn(__fmul_rn(r[2], SCALE), 0.5f);
    const float x2 = __fsub_rn(__fmul_rn(r[3], SCALE), 0.5f);
    const float y2 = __fsub_rn(__fmul_rn(r[4], SCALE), 0.5f);
    const float bw = __fdiv_rn(__fsub_rn(x2, x1), (float)OUTW);
    const float bh = __fdiv_rn(__fsub_rn(y2, y1), (float)OUTH);
    const float* fp = feat + (size_t)(b * CCH + c) * FHW;

    float acc = 0.f;
#pragma unroll
    for (int s = 0; s < 4; ++s) {
        const int sy = s >> 1, sx = s & 1;
        const float fy = (float)ph + (sy ? 0.75f : 0.25f);
        const float fx = (float)pw + (sx ? 0.75f : 0.25f);
        const float y = __fadd_rn(y1, __fmul_rn(fy, bh));
        const float x = __fadd_rn(x1, __fmul_rn(fx, bw));
        if (y > -1.0f && y < (float)FH && x > -1.0f && x < (float)FW) {
            const float yc = fmaxf(y, 0.0f);
            const float xc = fmaxf(x, 0.0f);
            int y0 = (int)yc; if (y0 > FH - 1) y0 = FH - 1;
            int x0 = (int)xc; if (x0 > FW - 1) x0 = FW - 1;
            const int y1i = min(y0 + 1, FH - 1);
            const int x1i = min(x0 + 1, FW - 1);
            const float ly = fminf(yc - (float)y0, 1.0f);
            const float lx = fminf(xc - (float)x0, 1.0f);
            const float hy = 1.0f - ly, hx = 1.0f - lx;
            acc += (hy * hx) * fp[y0  * FW + x0 ] + (hy * lx) * fp[y0  * FW + x1i]
                 + (ly * hx) * fp[y1i * FW + x0 ] + (ly * lx) * fp[y1i * FW + x1i];
        }
    }
    out[idx] = acc * 0.25f;
}

extern "C" void kernel_launch(void* const* d_in, const int* in_sizes, int n_in,
                              void* d_out, int out_size, void* d_ws, size_t ws_size,
                              hipStream_t stream) {
    const float* feat = (const float*)d_in[0];
    const float* rois = (const float*)d_in[1];
    float* out = (float*)d_out;

    const size_t nhwc_bytes = (size_t)NIMG * CCH * FHW * sizeof(__half);  // 16.8 MB
    const size_t need = nhwc_bytes + KROIS * sizeof(int) + 64;
    if (ws_size >= need) {
        __half* nhwc = (__half*)d_ws;
        int* perm = (int*)((char*)d_ws + nhwc_bytes);
        int* bases = perm + KROIS;
        prep_fused<<<dim3(8193), dim3(256), 0, stream>>>(feat, nhwc, rois, perm, bases);
        roi_align_nhwc<<<dim3(8 * MAXJ), dim3(256), 0, stream>>>(nhwc, rois, perm, bases, out);
    } else {
        const size_t total = (size_t)KROIS * CCH * NPIX;
        roi_align_naive<<<dim3((unsigned)((total + 255) / 256)), dim3(256), 0, stream>>>(feat, rois, out);
    }
}

// Round 12
// 43.206 us; speedup vs baseline: 1.4660x; 1.4660x over previous
//
#include <hip/hip_runtime.h>
#include <hip/hip_fp16.h>

#define NIMG 2
#define CCH 256
#define HALFC 128
#define FH 128
#define FW 128
#define FHW (FH * FW)
#define OUTH 7
#define OUTW 7
#define NPIX 49
#define NSAMP (NPIX * 4)
#define KROIS 1024
#define SCALE 0.0625f
#define OPITCH 132   // halves; 264 B row pitch
#define MAXJ 384     // block slots per XCD; j-loop handles overflow correctly

typedef float f32x4 __attribute__((ext_vector_type(4)));

// ---------------- fused: NCHW->NHWC fp16 transpose (blocks 0..8191) + ROI group sort (block 8192) ----
__global__ __launch_bounds__(256) void prep_fused(const float* __restrict__ in,
                                                  __half* __restrict__ out,
                                                  const float* __restrict__ rois,
                                                  int* __restrict__ perm,
                                                  int* __restrict__ bases) {
    const int bid = blockIdx.x;
    const int t = threadIdx.x;
    if (bid < 8192) {
        __shared__ float tile[32][33];
        const int b   = bid >> 12;
        const int rem = bid & 4095;
        const int c0  = (rem >> 9) << 5;
        const int hw0 = (rem & 511) << 5;
        const int tx = t & 31;
        const int ty = t >> 5;
        const float* src = in  + (size_t)b * CCH * FHW;
        __half*      dst = out + (size_t)b * FHW * CCH;
#pragma unroll
        for (int i = 0; i < 32; i += 8)
            tile[ty + i][tx] = src[(size_t)(c0 + ty + i) * FHW + hw0 + tx];
        __syncthreads();
#pragma unroll
        for (int i = 0; i < 32; i += 8)
            dst[(size_t)(hw0 + ty + i) * CCH + c0 + tx] = __float2half(tile[tx][ty + i]);
    } else {
        __shared__ int hist[128];
        __shared__ int basep[128];
        __shared__ int keyv[KROIS];
        __shared__ int rankv[KROIS];
        if (t < 128) hist[t] = 0;
        __syncthreads();
#pragma unroll
        for (int i = 0; i < 4; ++i) {
            const int roi = t + (i << 8);
            const float* r = rois + roi * 5;
            const int b = (int)r[0];
            const float cx = (r[1] + r[3]) * 0.5f * SCALE;
            const float cy = (r[2] + r[4]) * 0.5f * SCALE;
            const int qcx = min(max((int)cx, 0), FW - 1);
            const int qcy = min(max((int)cy, 0), FH - 1);
            const int g = (b << 1) | (qcy >> 6);                       // image, row-half
            const int cell = (((qcy & 63) >> 4) << 3) | (qcx >> 4);    // 4x8 16px cells
            const int key = (g << 5) | cell;
            keyv[roi] = key;
            rankv[roi] = atomicAdd(&hist[key], 1);
        }
        __syncthreads();
        if (t < 64) {  // one-wave exclusive scan over 128 bins (2/lane)
            const int a = hist[2 * t], c = hist[2 * t + 1];
            int s = a + c;
#pragma unroll
            for (int d = 1; d < 64; d <<= 1) {
                const int n = __shfl_up(s, d);
                if (t >= d) s += n;
            }
            const int excl = s - (a + c);
            basep[2 * t]     = excl;
            basep[2 * t + 1] = excl + a;
        }
        __syncthreads();
        if (t < 4) bases[t] = basep[t << 5];  // group starts
        if (t == 0) bases[4] = KROIS;
#pragma unroll
        for (int i = 0; i < 4; ++i) {
            const int roi = t + (i << 8);
            perm[basep[keyv[roi]] + rankv[roi]] = roi;
        }
    }
}

// ---------------- main RoIAlign: 8-way XCD partition = (channel-plane, image, row-half) ----------------
// R8 skeleton (proven best). Gather addressing scalarized: corner offsets are
// wave-uniform -> readfirstlane -> global_load with SGPR base + fixed VGPR laneoff.
__global__ __launch_bounds__(256, 4) void roi_align_nhwc(const __half* __restrict__ nhwc,
                                                         const float* __restrict__ rois,
                                                         const int* __restrict__ perm,
                                                         const int* __restrict__ bases,
                                                         float* __restrict__ out) {
    __shared__ __half obuf[NPIX * OPITCH];                 // 12,936 B
    __shared__ __align__(16) int   soff[NSAMP][4];         // 3,136 B
    __shared__ __align__(16) float swgt[NSAMP][4];         // 3,136 B
    const int bid = blockIdx.x;
    const int xcd = bid & 7;
    const int p = xcd >> 2;
    const int g = xcd & 3;
    const int base  = bases[g];
    const int count = bases[g + 1] - base;
    const int t = threadIdx.x;
    const int lane = t & 63;
    const int wave = t >> 6;
    const int pstart = wave ? (12 * wave + 1) : 0;          // 0,13,25,37
    const int pcnt   = wave ? 12 : 13;
    const int laneoff = (p << 8) + (lane << 2);             // plane + 2-ch lane slot (VGPR)

    for (int j = bid >> 3; j < count; j += MAXJ) {
        const int k = perm[base + j];
        const float* r = rois + k * 5;
        const int b = __builtin_amdgcn_readfirstlane((int)r[0]);

        // phase 0: one thread per (pix,sample) computes offsets+weights (exact ref math)
        if (t < NSAMP) {
            const float x1 = __fsub_rn(__fmul_rn(r[1], SCALE), 0.5f);
            const float y1 = __fsub_rn(__fmul_rn(r[2], SCALE), 0.5f);
            const float x2 = __fsub_rn(__fmul_rn(r[3], SCALE), 0.5f);
            const float y2 = __fsub_rn(__fmul_rn(r[4], SCALE), 0.5f);
            const float bw = __fdiv_rn(__fsub_rn(x2, x1), (float)OUTW);
            const float bh = __fdiv_rn(__fsub_rn(y2, y1), (float)OUTH);
            const int pix = t >> 2, s = t & 3;
            const int ph = pix / 7, pw = pix - ph * 7;
            const int sy = s >> 1, sx = s & 1;
            const float fy = (float)ph + (sy ? 0.75f : 0.25f);
            const float fx = (float)pw + (sx ? 0.75f : 0.25f);
            const float y = __fadd_rn(y1, __fmul_rn(fy, bh));
            const float x = __fadd_rn(x1, __fmul_rn(fx, bw));
            int o00 = 0, o01 = 0, o10 = 0, o11 = 0;
            float w00 = 0.f, w01 = 0.f, w10 = 0.f, w11 = 0.f;
            if (y > -1.0f && y < (float)FH && x > -1.0f && x < (float)FW) {
                const float yc = fmaxf(y, 0.0f);
                const float xc = fmaxf(x, 0.0f);
                int y0 = (int)yc; if (y0 > FH - 1) y0 = FH - 1;
                int x0 = (int)xc; if (x0 > FW - 1) x0 = FW - 1;
                const int y1i = min(y0 + 1, FH - 1);
                const int x1i = min(x0 + 1, FW - 1);
                const float ly = fminf(yc - (float)y0, 1.0f);
                const float lx = fminf(xc - (float)x0, 1.0f);
                const float hy = 1.0f - ly, hx = 1.0f - lx;
                w00 = hy * hx; w01 = hy * lx; w10 = ly * hx; w11 = ly * lx;
                o00 = (y0  * FW + x0 ) << 9;  // *512 B (256 fp16 channels per position)
                o01 = (y0  * FW + x1i) << 9;
                o10 = (y1i * FW + x0 ) << 9;
                o11 = (y1i * FW + x1i) << 9;
            }
            soff[t][0] = o00; soff[t][1] = o01; soff[t][2] = o10; soff[t][3] = o11;
            swgt[t][0] = w00; swgt[t][1] = w01; swgt[t][2] = w10; swgt[t][3] = w11;
        }
        __syncthreads();

        // phase 1: batch 16 dword loads per pixel into regs (saddr form), then fma_mix
        const char* gbase = (const char*)(nhwc + ((size_t)b * FHW << 8));
#pragma unroll
        for (int i = 0; i < 13; ++i) {
            if (i < pcnt) {
                const int pix = pstart + i;
                unsigned rv[16];
#pragma unroll
                for (int s = 0; s < 4; ++s) {
                    const int4 o = *(const int4*)(&soff[(pix << 2) + s][0]);
                    // offsets are wave-uniform -> hoist to SGPR; load = s[base]+v[laneoff]
                    const char* b0 = gbase + __builtin_amdgcn_readfirstlane(o.x);
                    const char* b1 = gbase + __builtin_amdgcn_readfirstlane(o.y);
                    const char* b2 = gbase + __builtin_amdgcn_readfirstlane(o.z);
                    const char* b3 = gbase + __builtin_amdgcn_readfirstlane(o.w);
                    rv[4 * s + 0] = *(const unsigned*)(b0 + laneoff);
                    rv[4 * s + 1] = *(const unsigned*)(b1 + laneoff);
                    rv[4 * s + 2] = *(const unsigned*)(b2 + laneoff);
                    rv[4 * s + 3] = *(const unsigned*)(b3 + laneoff);
                }
                float acc0 = 0.f, acc1 = 0.f;
#pragma unroll
                for (int s = 0; s < 4; ++s) {
                    const f32x4 w = *(const f32x4*)(&swgt[(pix << 2) + s][0]);
                    const __half2 A0 = *(const __half2*)&rv[4 * s + 0];
                    const __half2 A1 = *(const __half2*)&rv[4 * s + 1];
                    const __half2 A2 = *(const __half2*)&rv[4 * s + 2];
                    const __half2 A3 = *(const __half2*)&rv[4 * s + 3];
                    acc0 = fmaf(w.x, __half2float(A0.x), acc0);
                    acc1 = fmaf(w.x, __half2float(A0.y), acc1);
                    acc0 = fmaf(w.y, __half2float(A1.x), acc0);
                    acc1 = fmaf(w.y, __half2float(A1.y), acc1);
                    acc0 = fmaf(w.z, __half2float(A2.x), acc0);
                    acc1 = fmaf(w.z, __half2float(A2.y), acc1);
                    acc0 = fmaf(w.w, __half2float(A3.x), acc0);
                    acc1 = fmaf(w.w, __half2float(A3.y), acc1);
                }
                const __half2 h = __floats2half2_rn(acc0 * 0.25f, acc1 * 0.25f);
                *(unsigned*)&obuf[pix * OPITCH + (lane << 1)] = *(const unsigned*)&h;
            }
        }
        __syncthreads();

        // phase 2: coalesced writeout out[k][p*128 + c][pix], non-temporal.
        // Incremental (c,p) tracking -- no per-element integer division.
        float* op = out + (size_t)k * (CCH * NPIX) + (size_t)p * (HALFC * NPIX);
        {
            int f4 = t;
            int c  = (4 * t) / NPIX;       // single magic-mul div at entry
            int pp = 4 * t - NPIX * c;
#pragma unroll
            for (int n = 0; n < 7; ++n) {
                if (f4 < (HALFC * NPIX) / 4) {
                    const int c0 = c, p0 = pp;
                    int c1 = c0, p1 = p0 + 1; if (p1 >= NPIX) { p1 = 0; ++c1; }
                    int c2 = c1, p2 = p1 + 1; if (p2 >= NPIX) { p2 = 0; ++c2; }
                    int c3 = c2, p3 = p2 + 1; if (p3 >= NPIX) { p3 = 0; ++c3; }
                    f32x4 o;
                    o.x = __half2float(obuf[p0 * OPITCH + c0]);
                    o.y = __half2float(obuf[p1 * OPITCH + c1]);
                    o.z = __half2float(obuf[p2 * OPITCH + c2]);
                    o.w = __half2float(obuf[p3 * OPITCH + c3]);
                    __builtin_nontemporal_store(o, (f32x4*)(op + (f4 << 2)));
                    // advance by 1024 floats = 20*49 + 44
                    c += 20; pp += 44; if (pp >= NPIX) { pp -= NPIX; ++c; }
                    f4 += 256;
                }
            }
        }
        __syncthreads();  // protect obuf/soff/swgt before next j overwrites
    }
}

// ---------------- fallback: direct NCHW f32, one thread per output element ----------------
__global__ __launch_bounds__(256) void roi_align_naive(const float* __restrict__ feat,
                                                       const float* __restrict__ rois,
                                                       float* __restrict__ out) {
    const size_t idx = (size_t)blockIdx.x * 256 + threadIdx.x;
    const size_t total = (size_t)KROIS * CCH * NPIX;
    if (idx >= total) return;
    const int pix = (int)(idx % NPIX);
    const int t1  = (int)(idx / NPIX);
    const int c   = t1 % CCH;
    const int k   = t1 / CCH;
    const int ph = pix / 7;
    const int pw = pix - ph * 7;

    const float* r = rois + k * 5;
    const int b = (int)r[0];
    const float x1 = __fsub_rn(__fmul_rn(r[1], SCALE), 0.5f);
    const float y1 = __fsub_rn(__fmul_rn(r[2], SCALE), 0.5f);
    const float x2 = __fsub_rn(__fmul_rn(r[3], SCALE), 0.5f);
    const float y2 = __fsub_rn(__fmul_rn(r[4], SCALE), 0.5f);
    const float bw = __fdiv_rn(__fsub_rn(x2, x1), (float)OUTW);
    const float bh = __fdiv_rn(__fsub_rn(y2, y1), (float)OUTH);
    const float* fp = feat + (size_t)(b * CCH + c) * FHW;

    float acc = 0.f;
#pragma unroll
    for (int s = 0; s < 4; ++s) {
        const int sy = s >> 1, sx = s & 1;
        const float fy = (float)ph + (sy ? 0.75f : 0.25f);
        const float fx = (float)pw + (sx ? 0.75f : 0.25f);
        const float y = __fadd_rn(y1, __fmul_rn(fy, bh));
        const float x = __fadd_rn(x1, __fmul_rn(fx, bw));
        if (y > -1.0f && y < (float)FH && x > -1.0f && x < (float)FW) {
            const float yc = fmaxf(y, 0.0f);
            const float xc = fmaxf(x, 0.0f);
            int y0 = (int)yc; if (y0 > FH - 1) y0 = FH - 1;
            int x0 = (int)xc; if (x0 > FW - 1) x0 = FW - 1;
            const int y1i = min(y0 + 1, FH - 1);
            const int x1i = min(x0 + 1, FW - 1);
            const float ly = fminf(yc - (float)y0, 1.0f);
            const float lx = fminf(xc - (float)x0, 1.0f);
            const float hy = 1.0f - ly, hx = 1.0f - lx;
            acc += (hy * hx) * fp[y0  * FW + x0 ] + (hy * lx) * fp[y0  * FW + x1i]
                 + (ly * hx) * fp[y1i * FW + x0 ] + (ly * lx) * fp[y1i * FW + x1i];
        }
    }
    out[idx] = acc * 0.25f;
}

extern "C" void kernel_launch(void* const* d_in, const int* in_sizes, int n_in,
                              void* d_out, int out_size, void* d_ws, size_t ws_size,
                              hipStream_t stream) {
    const float* feat = (const float*)d_in[0];
    const float* rois = (const float*)d_in[1];
    float* out = (float*)d_out;

    const size_t nhwc_bytes = (size_t)NIMG * CCH * FHW * sizeof(__half);  // 16.8 MB
    const size_t need = nhwc_bytes + KROIS * sizeof(int) + 64;
    if (ws_size >= need) {
        __half* nhwc = (__half*)d_ws;
        int* perm = (int*)((char*)d_ws + nhwc_bytes);
        int* bases = perm + KROIS;
        prep_fused<<<dim3(8193), dim3(256), 0, stream>>>(feat, nhwc, rois, perm, bases);
        roi_align_nhwc<<<dim3(8 * MAXJ), dim3(256), 0, stream>>>(nhwc, rois, perm, bases, out);
    } else {
        const size_t total = (size_t)KROIS * CCH * NPIX;
        roi_align_naive<<<dim3((unsigned)((total + 255) / 256)), dim3(256), 0, stream>>>(feat, rois, out);
    }
}